// Round 8
// baseline (302.954 us; speedup 1.0000x reference)
//
#include <hip/hip_runtime.h>

typedef unsigned short u16;
typedef unsigned int u32;
typedef __attribute__((ext_vector_type(8))) short short8;
typedef __attribute__((ext_vector_type(4))) float f32x4;
typedef __attribute__((ext_vector_type(16))) float f32x16;
typedef __attribute__((ext_vector_type(4))) float float4v;
typedef __attribute__((ext_vector_type(4))) unsigned short u16x4;
typedef __attribute__((ext_vector_type(2))) u32 u32x2;

#define DEV __device__ __forceinline__

// 0.125 / ln(2): QK^T scale folded with exp->exp2 conversion
#define QSCALE 0.18033688011112042f

DEV u16 f2bf(float f) {
  u32 u = __float_as_uint(f);
  u32 r = (u + 0x7fffu + ((u >> 16) & 1u)) >> 16;
  return (u16)r;
}

// packed bf16 pair via HW cvt (RNE), lo -> bits[15:0], hi -> bits[31:16]
DEV u32 cvtpk(float lo, float hi) {
  u32 r;
  asm("v_cvt_pk_bf16_f32 %0, %1, %2" : "=v"(r) : "v"(lo), "v"(hi));
  return r;
}

DEV f32x4 mfma16(short8 a, short8 b, f32x4 c) {
  return __builtin_amdgcn_mfma_f32_16x16x32_bf16(a, b, c, 0, 0, 0);
}

DEV f32x16 mfma32(short8 a, short8 b, f32x16 c) {
  return __builtin_amdgcn_mfma_f32_32x32x16_bf16(a, b, c, 0, 0, 0);
}

DEV void gld_lds16(const void* g, void* l) {
  __builtin_amdgcn_global_load_lds(
      (const __attribute__((address_space(1))) void*)g,
      (__attribute__((address_space(3))) void*)l, 16, 0, 0);
}

// ---------------------------------------------------------------------------
// Convert X fp32 -> bf16, linear
__global__ void cvt_x_kernel(const float4v* __restrict__ in,
                             u32x2* __restrict__ out, int n4) {
  int i = blockIdx.x * blockDim.x + threadIdx.x;
  if (i >= n4) return;
  float4v v = in[i];
  u32x2 o;
  o.x = cvtpk(v.x, v.y);
  o.y = cvtpk(v.z, v.w);
  out[i] = o;
}

// Convert W fp32 [Kd][Nd] -> bf16 transposed [Nd][Kd]
__global__ void cvt_w_t_kernel(const float* __restrict__ in,
                               u16* __restrict__ out, int Kd, int Nd) {
  __shared__ float tile[32][33];
  int n0 = blockIdx.x * 32, k0 = blockIdx.y * 32;
  int tx = threadIdx.x, ty = threadIdx.y;
#pragma unroll
  for (int j = 0; j < 4; ++j)
    tile[ty + 8 * j][tx] = in[(size_t)(k0 + ty + 8 * j) * Nd + n0 + tx];
  __syncthreads();
#pragma unroll
  for (int j = 0; j < 4; ++j)
    out[(size_t)(n0 + ty + 8 * j) * Kd + k0 + tx] = f2bf(tile[tx][ty + 8 * j]);
}

// ---------------------------------------------------------------------------
// 128x128-tile bf16 GEMM, A [M][K] row-major, Bt [N][K] row-major (B^T).
// 1-D grid, XCD-swizzled. LDS chunk-XOR swizzle -> bank-even ds_read_b128.
// MODE 0: QKV epilogue -> Q [bh][t][d] (pre-scaled QSCALE), K [bh][t][d],
//         V transposed [bh][d][t], all bf16
// MODE 1: proj epilogue -> fp32 out [M][N] + bias
template <int MODE>
__global__ __launch_bounds__(256, 2) void gemm_bt(
    const u16* __restrict__ A, const u16* __restrict__ Bt,
    const float* __restrict__ bias, u16* __restrict__ q_out,
    u16* __restrict__ k_out, u16* __restrict__ vt_out,
    float* __restrict__ f_out, int M, int N, int K) {
  __shared__ u16 ldsA[128 * 64];
  __shared__ u16 ldsB[128 * 64];
  const int tid = threadIdx.x;
  const int lane = tid & 63, w = tid >> 6;
  const int g = lane >> 4, c = lane & 15;
  const int wm = w >> 1, wn = w & 1;

  // XCD-aware swizzle: grid is (N/128)*(M/128) blocks, divisible by 8.
  const int total = gridDim.x;
  const int cpx = total >> 3;
  const int wg = blockIdx.x;
  const int swz = (wg & 7) * cpx + (wg >> 3);
  const int mtiles = M >> 7;
  const int by = swz & (mtiles - 1);  // M-tile fastest (mtiles = 64, pow2)
  const int bx = swz / mtiles;
  const int n0 = bx * 128, m0 = by * 128;

  const f32x4 fz = {0.f, 0.f, 0.f, 0.f};
  f32x4 acc[4][4];
#pragma unroll
  for (int i = 0; i < 4; ++i)
#pragma unroll
    for (int j = 0; j < 4; ++j) acc[i][j] = fz;

  const u16* Ag = A + (size_t)m0 * K;
  const u16* Bg = Bt + (size_t)n0 * K;
  const int lr = lane >> 3;       // row within 8-row chunk
  const int kc = (lane & 7) ^ lr; // global k-chunk feeding swizzled LDS slot

  for (int kt = 0; kt < K; kt += 64) {
#pragma unroll
    for (int qq = 0; qq < 4; ++qq) {
      int row = w * 32 + qq * 8 + lr;
      gld_lds16(Ag + (size_t)row * K + kt + kc * 8, &ldsA[(w * 32 + qq * 8) * 64]);
      gld_lds16(Bg + (size_t)row * K + kt + kc * 8, &ldsB[(w * 32 + qq * 8) * 64]);
    }
    __syncthreads();
#pragma unroll
    for (int ks = 0; ks < 2; ++ks) {
      short8 ar[4], br[4];
#pragma unroll
      for (int mr = 0; mr < 4; ++mr) {
        int row = wm * 64 + mr * 16 + c;
        ar[mr] = *(const short8*)&ldsA[row * 64 + (((ks * 4 + g) ^ (row & 7)) << 3)];
      }
#pragma unroll
      for (int nf = 0; nf < 4; ++nf) {
        int row = wn * 64 + nf * 16 + c;
        br[nf] = *(const short8*)&ldsB[row * 64 + (((ks * 4 + g) ^ (row & 7)) << 3)];
      }
#pragma unroll
      for (int mr = 0; mr < 4; ++mr)
#pragma unroll
        for (int nf = 0; nf < 4; ++nf)
          acc[mr][nf] = mfma16(ar[mr], br[nf], acc[mr][nf]);
    }
    __syncthreads();
  }

#pragma unroll
  for (int mr = 0; mr < 4; ++mr) {
#pragma unroll
    for (int nf = 0; nf < 4; ++nf) {
      const int gm0 = m0 + wm * 64 + mr * 16 + 4 * g;
      const int gn = n0 + wn * 64 + nf * 16 + c;
      float v4[4];
#pragma unroll
      for (int r = 0; r < 4; ++r) v4[r] = acc[mr][nf][r] + bias[gn];
      if (MODE == 0) {
        const int sec = gn >> 10, cc = gn & 1023;
        const int hh = cc >> 6, dd = cc & 63;
        const int bb = gm0 >> 11, tt0 = gm0 & 2047;
        if (sec == 0) {
#pragma unroll
          for (int r = 0; r < 4; ++r)
            q_out[((size_t)(bb * 16 + hh) * 2048 + tt0 + r) * 64 + dd] =
                f2bf(v4[r] * QSCALE);
        } else if (sec == 1) {
#pragma unroll
          for (int r = 0; r < 4; ++r)
            k_out[((size_t)(bb * 16 + hh) * 2048 + tt0 + r) * 64 + dd] =
                f2bf(v4[r]);
        } else {
          // V^T: r -> consecutive t, one 8B packed store
          u32x2 pkd;
          pkd.x = cvtpk(v4[0], v4[1]);
          pkd.y = cvtpk(v4[2], v4[3]);
          *(u32x2*)&vt_out[((size_t)(bb * 16 + hh) * 64 + dd) * 2048 + tt0] = pkd;
        }
      } else {
#pragma unroll
        for (int r = 0; r < 4; ++r)
          f_out[(size_t)(gm0 + r) * N + gn] = v4[r];
      }
    }
  }
}

// ---------------------------------------------------------------------------
// Flash attention fwd, causal, 32x32x16 MFMA. Block = 128 queries of one
// (b,h); 4 waves x 32q. K tile [64k][64d] + V^T tile [64d][64k] LDS-staged,
// double-buffered, chunk-XOR swizzled. Swapped QK^T (mfma(K,Q)) -> P C-layout
// col = query = lane&31: softmax state lane-local. Lane half h=lane>>5 holds
// keys offset 4h; P->PV B-operand needs only a lane<->lane+32 pair exchange
// (2 shfl_xor per 16-key group). PV: o^T = mfma(V^T, P).
// Q pre-scaled 0.125/ln2; exp2 softmax; defer-max rescale (THR=8, log2).
__global__ __launch_bounds__(256, 3) void attn_fwd(
    const u16* __restrict__ Qb, const u16* __restrict__ Kb,
    const u16* __restrict__ VTb, u16* __restrict__ Ob) {
  __shared__ u16 lds[2][8192];  // per buf: K at [0..4095], VT at [4096..8191]
  const int lane = threadIdx.x & 63, w = threadIdx.x >> 6;  // w = 0..3
  const int h = lane >> 5;      // key-offset half
  const int q5 = lane & 31;     // query (and A-row) index
  const int l7 = lane & 7;
  const int bi = blockIdx.x;
  const int bh = ((bi & 7) << 3) | ((bi >> 3) & 7);  // 8 heads per XCD
  const int qblock = 15 - (bi >> 6);                 // longest blocks first
  const int b = bh >> 4, hd = bh & 15;
  const size_t base = (size_t)bh * (2048 * 64);
  const u16* Qp = Qb + base;
  const u16* Kp = Kb + base;
  const u16* VTp = VTb + base;

  const int qw = qblock * 128 + w * 32;  // wave's first query
  const int qg = qw + q5;                // this lane's query
  const int nt = 2 * qblock + 2;         // 64-key tiles for this block
  const int tmask = qw >> 6;             // == t: partial; > t: full; skip rest

  short8 qf[4];
#pragma unroll
  for (int dc = 0; dc < 4; ++dc)
    qf[dc] = *(const short8*)&Qp[(qw + q5) * 64 + dc * 16 + h * 8];

  const f32x16 z16 = {0.f, 0.f, 0.f, 0.f, 0.f, 0.f, 0.f, 0.f,
                      0.f, 0.f, 0.f, 0.f, 0.f, 0.f, 0.f, 0.f};
  f32x16 o0 = z16, o1 = z16;  // O^T d-blocks 0..31 / 32..63, col=q
  float m = -1e30f, lsum = 0.f;

  // staging: 16 regions of 1KB, 4 per wave; i<8 = K rows 8i.., i>=8 = VT rows
  const int srow = lane >> 3;                    // row within 8-row region
  const int sgx = (lane & 7) ^ (srow & 7);       // pre-swizzled global chunk
  auto stage = [&](int t, int buf) {
#pragma unroll
    for (int q = 0; q < 4; ++q) {
      const int i = w * 4 + q;
      const int row = ((i & 7) << 3) | srow;
      const int k0 = t << 6;
      const u16* src = (i < 8)
          ? Kp + (size_t)(k0 + row) * 64 + sgx * 8
          : VTp + (size_t)row * 2048 + k0 + sgx * 8;
      gld_lds16(src, &lds[buf][i * 512]);
    }
  };

  stage(0, 0);
  __syncthreads();

  for (int t = 0; t < nt; ++t) {
    const int cur = t & 1;
    if (t + 1 < nt) stage(t + 1, cur ^ 1);
    if (t <= tmask) {
      const u16* Kl = &lds[cur][0];
      const u16* Vl = &lds[cur][4096];
      const int k0b = t << 6;
      // kb2=1 (keys 32..63) active unless diagonal tile with qw%64==0
      const bool full2 = !(t == tmask && !(qw & 32));

      // --- QK^T: A=K (rows=keys), B=Q (cols=queries) ---
      f32x16 p0 = z16, p1 = z16;
      __builtin_amdgcn_s_setprio(1);
#pragma unroll
      for (int dc = 0; dc < 4; ++dc) {
        short8 kf = *(const short8*)&Kl[q5 * 64 + (((dc * 2 + h) ^ l7) << 3)];
        p0 = mfma32(kf, qf[dc], p0);
      }
      if (full2) {
#pragma unroll
        for (int dc = 0; dc < 4; ++dc) {
          short8 kf =
              *(const short8*)&Kl[(32 + q5) * 64 + (((dc * 2 + h) ^ l7) << 3)];
          p1 = mfma32(kf, qf[dc], p1);
        }
      }
      __builtin_amdgcn_s_setprio(0);

      // --- causal mask (diagonal tile only) ---
      if (t == tmask) {
        if (qw & 32) {
#pragma unroll
          for (int reg = 0; reg < 16; ++reg) {
            int key = k0b + 32 + (reg & 3) + 8 * (reg >> 2) + 4 * h;
            if (key > qg) p1[reg] = -1e30f;
          }
        } else {
#pragma unroll
          for (int reg = 0; reg < 16; ++reg) {
            int key = k0b + (reg & 3) + 8 * (reg >> 2) + 4 * h;
            if (key > qg) p0[reg] = -1e30f;
          }
        }
      }

      // --- online softmax (q lane-local; partner lane^32 has same q) ---
      float tm = p0[0];
#pragma unroll
      for (int reg = 1; reg < 16; ++reg) tm = fmaxf(tm, p0[reg]);
      if (full2) {
#pragma unroll
        for (int reg = 0; reg < 16; ++reg) tm = fmaxf(tm, p1[reg]);
      }
      tm = fmaxf(tm, __shfl_xor(tm, 32));

      if (__any(tm > m + 8.f)) {  // defer-max
        float mn = fmaxf(m, tm);
        float sc = __builtin_amdgcn_exp2f(m - mn);
        m = mn;
        lsum *= sc;
#pragma unroll
        for (int reg = 0; reg < 16; ++reg) {
          o0[reg] *= sc;
          o1[reg] *= sc;
        }
      }

      float rs = 0.f;
#pragma unroll
      for (int reg = 0; reg < 16; ++reg) {
        p0[reg] = __builtin_amdgcn_exp2f(p0[reg] - m);
        rs += p0[reg];
      }
      if (full2) {
#pragma unroll
        for (int reg = 0; reg < 16; ++reg) {
          p1[reg] = __builtin_amdgcn_exp2f(p1[reg] - m);
          rs += p1[reg];
        }
      }
      rs += __shfl_xor(rs, 32);
      lsum += rs;

      // --- pack P: W2[i=kb2*4+r2] = keys 32*kb2+8*r2+4h+{0..3} (2 u32) ---
      u32 W2lo[8], W2hi[8];
#pragma unroll
      for (int r2 = 0; r2 < 4; ++r2) {
        W2lo[r2] = cvtpk(p0[4 * r2 + 0], p0[4 * r2 + 1]);
        W2hi[r2] = cvtpk(p0[4 * r2 + 2], p0[4 * r2 + 3]);
      }
      if (full2) {
#pragma unroll
        for (int r2 = 0; r2 < 4; ++r2) {
          W2lo[4 + r2] = cvtpk(p1[4 * r2 + 0], p1[4 * r2 + 1]);
          W2hi[4 + r2] = cvtpk(p1[4 * r2 + 2], p1[4 * r2 + 3]);
        }
      }

      // --- PV: for each 16-key group kg, B-frag = keys 16kg+8h+e ---
      const int nkg = full2 ? 4 : 2;
      for (int kg = 0; kg < nkg; ++kg) {
        // lane needs W2[2kg+h] from both halves; partner wants W2[2kg+1-h]
        u32 slo = h ? W2lo[2 * kg] : W2lo[2 * kg + 1];
        u32 shi = h ? W2hi[2 * kg] : W2hi[2 * kg + 1];
        u32 rlo = (u32)__shfl_xor((int)slo, 32);
        u32 rhi = (u32)__shfl_xor((int)shi, 32);
        union { u32 u[4]; short8 s; } pb;
        pb.u[0] = h ? rlo : W2lo[2 * kg];      // e0..3 (from h_src=0)
        pb.u[1] = h ? rhi : W2hi[2 * kg];
        pb.u[2] = h ? W2lo[2 * kg + 1] : rlo;  // e4..7 (from h_src=1)
        pb.u[3] = h ? W2hi[2 * kg + 1] : rhi;

        __builtin_amdgcn_s_setprio(1);
        short8 va0 =
            *(const short8*)&Vl[q5 * 64 + (((kg * 2 + h) ^ l7) << 3)];
        o0 = mfma32(va0, pb.s, o0);
        short8 va1 =
            *(const short8*)&Vl[(32 + q5) * 64 + (((kg * 2 + h) ^ l7) << 3)];
        o1 = mfma32(va1, pb.s, o1);
        __builtin_amdgcn_s_setprio(0);
      }
    }
    __syncthreads();
  }

  // --- normalize + write: lane holds O[q=q5][d = 32*db + 8*r2 + 4h + r] ---
  float inv = 1.f / lsum;
  u16* Op = Ob + (size_t)(b * 2048 + qw + q5) * 1024 + hd * 64;
#pragma unroll
  for (int r2 = 0; r2 < 4; ++r2) {
    u32x2 pk0, pk1;
    pk0.x = cvtpk(o0[4 * r2 + 0] * inv, o0[4 * r2 + 1] * inv);
    pk0.y = cvtpk(o0[4 * r2 + 2] * inv, o0[4 * r2 + 3] * inv);
    *(u32x2*)(Op + 8 * r2 + 4 * h) = pk0;
    pk1.x = cvtpk(o1[4 * r2 + 0] * inv, o1[4 * r2 + 1] * inv);
    pk1.y = cvtpk(o1[4 * r2 + 2] * inv, o1[4 * r2 + 3] * inv);
    *(u32x2*)(Op + 32 + 8 * r2 + 4 * h) = pk1;
  }
}

// ---------------------------------------------------------------------------
extern "C" void kernel_launch(void* const* d_in, const int* in_sizes, int n_in,
                              void* d_out, int out_size, void* d_ws,
                              size_t ws_size, hipStream_t stream) {
  (void)in_sizes; (void)n_in; (void)out_size; (void)ws_size;
  const float* X = (const float*)d_in[0];
  const float* Wqkv = (const float*)d_in[1];
  const float* bqkv = (const float*)d_in[2];
  const float* Wproj = (const float*)d_in[3];
  const float* bproj = (const float*)d_in[4];
  float* out = (float*)d_out;

  char* ws = (char*)d_ws;
  u16* Xb = (u16*)ws;                          // 16 MiB [8192][1024] bf16 (also O)
  u16* WqkvT = (u16*)(ws + (16u << 20));       // 6 MiB  [3072][1024]
  u16* WprojT = (u16*)(ws + (22u << 20));      // 2 MiB  [1024][1024]
  u16* Qb = (u16*)(ws + (24u << 20));          // 16 MiB [bh][t][d], pre-scaled
  u16* Kb = (u16*)(ws + (40u << 20));          // 16 MiB [bh][t][d]
  u16* VT = (u16*)(ws + (56u << 20));          // 16 MiB [bh][d][t]

  cvt_x_kernel<<<dim3(8192), dim3(256), 0, stream>>>(
      (const float4v*)X, (u32x2*)Xb, 8192 * 1024 / 4);
  cvt_w_t_kernel<<<dim3(96, 32), dim3(32, 8), 0, stream>>>(Wqkv, WqkvT, 1024, 3072);
  cvt_w_t_kernel<<<dim3(32, 32), dim3(32, 8), 0, stream>>>(Wproj, WprojT, 1024, 1024);

  gemm_bt<0><<<dim3(1536), dim3(256), 0, stream>>>(
      Xb, WqkvT, bqkv, Qb, Kb, VT, (float*)nullptr, 8192, 3072, 1024);

  attn_fwd<<<dim3(1024), dim3(256), 0, stream>>>(Qb, Kb, VT, Xb);

  gemm_bt<1><<<dim3(512), dim3(256), 0, stream>>>(
      Xb, WprojT, bproj, (u16*)nullptr, (u16*)nullptr, (u16*)nullptr, out,
      8192, 1024, 1024);
}